// Round 1
// baseline (417.742 us; speedup 1.0000x reference)
//
#include <hip/hip_runtime.h>

typedef unsigned int uint;
typedef __bf16 bf16_t;
typedef bf16_t bf16x8 __attribute__((ext_vector_type(8)));
typedef float floatx4 __attribute__((ext_vector_type(4)));

struct __align__(8) us4 { unsigned short x, y, z, w; };

__device__ __forceinline__ unsigned short f2b(float f) {
    unsigned u = __float_as_uint(f);
    u = u + 0x7FFFu + ((u >> 16) & 1u);   // RNE
    return (unsigned short)(u >> 16);
}
__device__ __forceinline__ float b2f(unsigned short h) {
    return __uint_as_float(((unsigned)h) << 16);
}

// async global->LDS, 16B per lane; LDS dest is wave-uniform base + lane*16
__device__ __forceinline__ void g2l16(const void* g, void* l) {
    __builtin_amdgcn_global_load_lds((__attribute__((address_space(1))) void*)g,
                                     (__attribute__((address_space(3))) void*)l,
                                     16, 0, 0);
}

__device__ __forceinline__ float wave_max(float v) {
#pragma unroll
    for (int m = 32; m > 0; m >>= 1) v = fmaxf(v, __shfl_xor(v, m));
    return v;
}
__device__ __forceinline__ float wave_sum(float v) {
#pragma unroll
    for (int m = 32; m > 0; m >>= 1) v += __shfl_xor(v, m);
    return v;
}

// ---------------------------------------------------------------------------
// gemm_bt: O[m,n] = sum_k A[m,k] * B[n,k]   (both operands row-major, K inner)
// 128x128 block tile, BK=32, 4 waves in 2x2, each wave 4x4 of 16x16x32 MFMA.
// MODE 0: bf16 store O[m*ldo+n]
// MODE 1: bf16 TRANSPOSED store into OT[b, n, m%seqN]  (b = m/seqN, ldo=cols)
// MODE 2: bf16 store of (acc + R[m*ldo+n])   (residual add)
// MODE 3: f32  store of (acc + R[m*ldo+n])
// ---------------------------------------------------------------------------
template <int MODE>
__global__ __launch_bounds__(256, 2) void gemm_bt(
    const unsigned short* __restrict__ A, const unsigned short* __restrict__ B,
    void* __restrict__ O, const unsigned short* __restrict__ R,
    int K, int lda, int ldb, int ldo,
    long long sA, long long sB, long long sO, long long sR, int seqN)
{
    __shared__ __attribute__((aligned(16))) unsigned short As[128 * 32];
    __shared__ __attribute__((aligned(16))) unsigned short Bs[128 * 32];

    const int bz = blockIdx.z;
    const unsigned short* Ab = A + (long long)bz * sA;
    const unsigned short* Bb = B + (long long)bz * sB;
    const int m0 = blockIdx.x * 128;
    const int n0 = blockIdx.y * 128;
    const int tid = threadIdx.x;
    const int l = tid & 63;
    const int w = tid >> 6;
    const int wm = (w >> 1) * 64;
    const int wn = (w & 1) * 64;

    // staging: thread t covers row (t>>2), 16B chunk (t&3) of the 64B row
    const int srow = tid >> 2;
    const int scol = (tid & 3) * 8;
    const unsigned short* ga = Ab + (long long)(m0 + srow) * lda + scol;
    const unsigned short* gb = Bb + (long long)(n0 + srow) * ldb + scol;
    unsigned short* la = As + tid * 8;   // byte offset tid*16 == row*64 + chunk*16
    unsigned short* lb = Bs + tid * 8;

    const int fr = l & 15;        // m/n within 16-tile
    const int kq = (l >> 4) * 8;  // k offset within 32

    floatx4 acc[4][4] = {};

    for (int kt = 0; kt < K; kt += 32) {
        __syncthreads();                       // previous tile fully consumed
        g2l16(ga, la);
        g2l16(ga + (long long)64 * lda, la + 64 * 32);
        g2l16(gb, lb);
        g2l16(gb + (long long)64 * ldb, lb + 64 * 32);
        ga += 32; gb += 32;
        __syncthreads();                       // staging complete (vmcnt drain)

        bf16x8 af[4], bfr[4];
#pragma unroll
        for (int i = 0; i < 4; ++i) {
            af[i]  = *(const bf16x8*)(As + (wm + i * 16 + fr) * 32 + kq);
            bfr[i] = *(const bf16x8*)(Bs + (wn + i * 16 + fr) * 32 + kq);
        }
#pragma unroll
        for (int i = 0; i < 4; ++i)
#pragma unroll
            for (int j = 0; j < 4; ++j)
                acc[i][j] = __builtin_amdgcn_mfma_f32_16x16x32_bf16(
                    af[i], bfr[j], acc[i][j], 0, 0, 0);
    }

    // C/D layout (verified m89/m91): col = lane&15, row = (lane>>4)*4 + reg
    const int col = l & 15;
    const int rbase = (l >> 4) * 4;

    if constexpr (MODE == 1) {
        unsigned short* Ot = (unsigned short*)O;
        const int b = m0 / seqN;
        const int mqb = m0 - b * seqN;
#pragma unroll
        for (int i = 0; i < 4; ++i) {
#pragma unroll
            for (int j = 0; j < 4; ++j) {
                int gn = n0 + wn + j * 16 + col;
                int mq = mqb + wm + i * 16 + rbase;   // 4 consecutive m per lane
                us4 pk = { f2b(acc[i][j][0]), f2b(acc[i][j][1]),
                           f2b(acc[i][j][2]), f2b(acc[i][j][3]) };
                *(us4*)(Ot + ((long long)b * ldo + gn) * seqN + mq) = pk;
            }
        }
    } else {
#pragma unroll
        for (int i = 0; i < 4; ++i) {
#pragma unroll
            for (int j = 0; j < 4; ++j) {
                int gn = n0 + wn + j * 16 + col;
                int gmb = m0 + wm + i * 16 + rbase;
#pragma unroll
                for (int r = 0; r < 4; ++r) {
                    long long idx = (long long)(gmb + r) * ldo + gn;
                    float v = acc[i][j][r];
                    if constexpr (MODE == 0) {
                        ((unsigned short*)O + bz * sO)[idx] = f2b(v);
                    } else if constexpr (MODE == 2) {
                        const unsigned short* Rb = R + bz * sR;
                        ((unsigned short*)O + bz * sO)[idx] = f2b(v + b2f(Rb[idx]));
                    } else {
                        const unsigned short* Rb = R + bz * sR;
                        ((float*)O + bz * sO)[idx] = v + b2f(Rb[idx]);
                    }
                }
            }
        }
    }
}

// ---------------------------------------------------------------------------
// conversions
// ---------------------------------------------------------------------------
__global__ __launch_bounds__(256) void f32_to_bf16_k(const float* __restrict__ in,
                                                     unsigned short* __restrict__ out)
{
    long long i = ((long long)blockIdx.x * 256 + threadIdx.x) * 4;
    float4 v = *(const float4*)(in + i);
    us4 o = { f2b(v.x), f2b(v.y), f2b(v.z), f2b(v.w) };
    *(us4*)(out + i) = o;
}

struct WPtrs { const float* in[5]; unsigned short* out[5]; };
__global__ __launch_bounds__(256) void conv_weights(WPtrs p)
{
    int which = blockIdx.y;
    long long i = ((long long)blockIdx.x * 256 + threadIdx.x) * 4;
    float4 v = *(const float4*)(p.in[which] + i);
    us4 o = { f2b(v.x), f2b(v.y), f2b(v.z), f2b(v.w) };
    *(us4*)(p.out[which] + i) = o;
}

// ---------------------------------------------------------------------------
// softmax over rows of length 512, in place, times `scale` (q path)
// ---------------------------------------------------------------------------
__global__ __launch_bounds__(256) void softmax_row512(unsigned short* __restrict__ q,
                                                      float scale)
{
    __shared__ float red[8];
    unsigned short* p = q + (long long)blockIdx.x * 512;
    int t = threadIdx.x;
    uint v = *(const uint*)(p + 2 * t);
    float a = b2f((unsigned short)(v & 0xffff));
    float b = b2f((unsigned short)(v >> 16));
    float mx = wave_max(fmaxf(a, b));
    int w = t >> 6;
    if ((t & 63) == 0) red[w] = mx;
    __syncthreads();
    mx = fmaxf(fmaxf(red[0], red[1]), fmaxf(red[2], red[3]));
    float ea = __expf(a - mx), eb = __expf(b - mx);
    float s = wave_sum(ea + eb);
    if ((t & 63) == 0) red[4 + w] = s;
    __syncthreads();
    s = red[4] + red[5] + red[6] + red[7];
    float inv = scale / s;
    uint o = (uint)f2b(ea * inv) | ((uint)f2b(eb * inv) << 16);
    *(uint*)(p + 2 * t) = o;
}

// ---------------------------------------------------------------------------
// softmax over rows of length 4096, in place (k path, rows = (b,c) of kT)
// ---------------------------------------------------------------------------
__global__ __launch_bounds__(256) void softmax_row4096(unsigned short* __restrict__ kk)
{
    __shared__ float red[8];
    unsigned short* p = kk + (long long)blockIdx.x * 4096;
    int t = threadIdx.x;
    uint4 v0 = *(const uint4*)(p + 16 * t);
    uint4 v1 = *(const uint4*)(p + 16 * t + 8);
    uint u[8] = { v0.x, v0.y, v0.z, v0.w, v1.x, v1.y, v1.z, v1.w };
    float f[16];
#pragma unroll
    for (int i = 0; i < 8; ++i) {
        f[2 * i]     = b2f((unsigned short)(u[i] & 0xffff));
        f[2 * i + 1] = b2f((unsigned short)(u[i] >> 16));
    }
    float mx = f[0];
#pragma unroll
    for (int i = 1; i < 16; ++i) mx = fmaxf(mx, f[i]);
    mx = wave_max(mx);
    int w = t >> 6;
    if ((t & 63) == 0) red[w] = mx;
    __syncthreads();
    mx = fmaxf(fmaxf(red[0], red[1]), fmaxf(red[2], red[3]));
    float s = 0.f;
#pragma unroll
    for (int i = 0; i < 16; ++i) { f[i] = __expf(f[i] - mx); s += f[i]; }
    s = wave_sum(s);
    if ((t & 63) == 0) red[4 + w] = s;
    __syncthreads();
    s = red[4] + red[5] + red[6] + red[7];
    float inv = 1.f / s;
    uint o[8];
#pragma unroll
    for (int i = 0; i < 8; ++i)
        o[i] = (uint)f2b(f[2 * i] * inv) | ((uint)f2b(f[2 * i + 1] * inv) << 16);
    *(uint4*)(p + 16 * t)     = make_uint4(o[0], o[1], o[2], o[3]);
    *(uint4*)(p + 16 * t + 8) = make_uint4(o[4], o[5], o[6], o[7]);
}

// ---------------------------------------------------------------------------
extern "C" void kernel_launch(void* const* d_in, const int* in_sizes, int n_in,
                              void* d_out, int out_size, void* d_ws, size_t ws_size,
                              hipStream_t stream)
{
    (void)in_sizes; (void)n_in; (void)out_size; (void)ws_size;
    const float* x  = (const float*)d_in[0];
    const float* Wq = (const float*)d_in[1];
    const float* Wk = (const float*)d_in[2];
    const float* Wv = (const float*)d_in[3];
    const float* W1 = (const float*)d_in[4];
    const float* W2 = (const float*)d_in[5];
    float* out = (float*)d_out;

    const int Bn = 8, N = 4096, C = 512;
    const long long M  = (long long)Bn * N;   // 32768
    const long long XE = M * C;               // 16,777,216 elements

    char* ws = (char*)d_ws;
    size_t off = 0;
    auto carve = [&](size_t bytes) -> void* {
        void* p = ws + off;
        off += (bytes + 255) & ~(size_t)255;
        return p;
    };

    unsigned short* xb   = (unsigned short*)carve(XE * 2);
    unsigned short* wqb  = (unsigned short*)carve((size_t)C * C * 2);
    unsigned short* wkb  = (unsigned short*)carve((size_t)C * C * 2);
    unsigned short* wvb  = (unsigned short*)carve((size_t)C * C * 2);
    unsigned short* w1b  = (unsigned short*)carve((size_t)C * C * 2);
    unsigned short* w2b  = (unsigned short*)carve((size_t)C * C * 2);
    unsigned short* q    = (unsigned short*)carve(XE * 2);
    unsigned short* kT   = (unsigned short*)carve(XE * 2);   // [b, c, n]
    unsigned short* vT   = (unsigned short*)carve(XE * 2);   // [b, c, n]
    unsigned short* ctxT = (unsigned short*)carve((size_t)Bn * C * C * 2); // [b, e, d]
    unsigned short* xr = kT;   // alias: kT dead after ctx gemm
    unsigned short* h  = vT;   // alias: vT dead after ctx gemm

    // dtype conversions
    f32_to_bf16_k<<<dim3((unsigned)(XE / 1024)), dim3(256), 0, stream>>>(x, xb);
    WPtrs wp = { { Wq, Wk, Wv, W1, W2 }, { wqb, wkb, wvb, w1b, w2b } };
    conv_weights<<<dim3((C * C) / 1024, 5), dim3(256), 0, stream>>>(wp);

    // q = x@Wq.T ; kT = (x@Wk.T)^T ; vT = (x@Wv.T)^T   (transposed epilogue)
    gemm_bt<0><<<dim3(M / 128, C / 128, 1), 256, 0, stream>>>(
        xb, wqb, q, nullptr, C, C, C, C, 0, 0, 0, 0, 0);
    gemm_bt<1><<<dim3(M / 128, C / 128, 1), 256, 0, stream>>>(
        xb, wkb, kT, nullptr, C, C, C, C, 0, 0, 0, 0, N);
    gemm_bt<1><<<dim3(M / 128, C / 128, 1), 256, 0, stream>>>(
        xb, wvb, vT, nullptr, C, C, C, C, 0, 0, 0, 0, N);

    // softmaxes (in place)
    softmax_row512<<<dim3((unsigned)M), 256, 0, stream>>>(q, 0.044194173824159216f);
    softmax_row4096<<<dim3(Bn * C), 256, 0, stream>>>(kT);

    // ctxT[b,e,d] = sum_n vT[b,e,n] * kT[b,d,n]
    gemm_bt<0><<<dim3(C / 128, C / 128, Bn), 256, 0, stream>>>(
        vT, kT, ctxT, nullptr, N, N, N, C,
        (long long)C * N, (long long)C * N, (long long)C * C, 0, 0);

    // xr[b,n,e] = sum_d q[b,n,d] * ctxT[b,e,d] + x[b,n,e]
    gemm_bt<2><<<dim3(N / 128, C / 128, Bn), 256, 0, stream>>>(
        q, ctxT, xr, xb, C, C, C, C,
        (long long)N * C, (long long)C * C, (long long)N * C, (long long)N * C, 0);

    // h = xr @ W1.T
    gemm_bt<0><<<dim3(M / 128, C / 128, 1), 256, 0, stream>>>(
        xr, w1b, h, nullptr, C, C, C, C, 0, 0, 0, 0, 0);

    // out = h @ W2.T + xr   (fp32 output)
    gemm_bt<3><<<dim3(M / 128, C / 128, 1), 256, 0, stream>>>(
        h, w2b, out, xr, C, C, C, C, 0, 0, 0, 0, 0);
}